// Round 4
// baseline (316.828 us; speedup 1.0000x reference)
//
#include <hip/hip_runtime.h>
#include <hip/hip_bf16.h>

typedef __attribute__((ext_vector_type(8))) short short8;
typedef __attribute__((ext_vector_type(4))) float f32x4;

#define EPS 1e-5f

__device__ __forceinline__ unsigned short f2bf(float f) {
    union { float f; unsigned u; } v; v.f = f;
    unsigned u = v.u;
    u += 0x7FFFu + ((u >> 16) & 1u);   // RNE
    return (unsigned short)(u >> 16);
}
__device__ __forceinline__ float bflo(unsigned u) {
    union { unsigned u; float f; } v; v.u = u << 16; return v.f;
}
__device__ __forceinline__ float bfhi(unsigned u) {
    union { unsigned u; float f; } v; v.u = u & 0xffff0000u; return v.f;
}
__device__ __forceinline__ float bf2f(ushort u) {
    union { unsigned u; float f; } v; v.u = ((unsigned)u) << 16; return v.f;
}

// ---------------- K0: one-time conversion f32 -> bf16 (weights + x) --------
__global__ __launch_bounds__(256) void k_prep(
        const float* __restrict__ ipw, const float* __restrict__ ow,
        const float* __restrict__ w1, const float* __restrict__ w2,
        const float* __restrict__ x,
        ushort* __restrict__ wqb, ushort* __restrict__ wob,
        ushort* __restrict__ w1b, ushort* __restrict__ w2b,
        ushort* __restrict__ xb, int nx) {
    int i = blockIdx.x * 256 + threadIdx.x;
    if (i < 49152) wqb[i] = f2bf(ipw[i]);
    if (i < 16384) wob[i] = f2bf(ow[i]);
    if (i < 65536) { w1b[i] = f2bf(w1[i]); w2b[i] = f2bf(w2[i]); }
    // x conversion, 4 elements/thread, grid-stride
    int stride = gridDim.x * 256 * 4;
    for (int j = i * 4; j < nx; j += stride) {
        f32x4 v = *(const f32x4*)(x + j);
        uint2 o;
        o.x = (unsigned)f2bf(v[0]) | ((unsigned)f2bf(v[1]) << 16);
        o.y = (unsigned)f2bf(v[2]) | ((unsigned)f2bf(v[3]) << 16);
        *(uint2*)(xb + j) = o;
    }
}

// ---------------- K1: qkv = x @ in_proj_w^T + b  (bf16 in/out) -------------
__global__ __launch_bounds__(256) void k_qkv(
        const ushort* __restrict__ xb, const ushort* __restrict__ w,
        const float* __restrict__ bias, ushort* __restrict__ qkv, int N) {
    const int wave = threadIdx.x >> 6, lane = threadIdx.x & 63;
    const int l16 = lane & 15, l4 = lane >> 4;
    const int base = blockIdx.x * 64;

    short8 af[4][4];
    #pragma unroll
    for (int mt = 0; mt < 4; ++mt) {
        int row = base + mt*16 + l16;
        int rc = row < N ? row : N - 1;
        const ushort* p = xb + (size_t)rc*128 + l4*8;
        #pragma unroll
        for (int kb = 0; kb < 4; ++kb) af[mt][kb] = *(const short8*)(p + kb*32);
    }
    #pragma unroll
    for (int i = 0; i < 6; ++i) {
        int col = (wave*6 + i)*16 + l16;
        const ushort* pw = w + (size_t)col*128 + l4*8;
        short8 bf[4];
        #pragma unroll
        for (int kb = 0; kb < 4; ++kb) bf[kb] = *(const short8*)(pw + kb*32);
        float bv = bias[col];
        #pragma unroll
        for (int mt = 0; mt < 4; ++mt) {
            f32x4 acc = {0.f, 0.f, 0.f, 0.f};
            #pragma unroll
            for (int kb = 0; kb < 4; ++kb)
                acc = __builtin_amdgcn_mfma_f32_16x16x32_bf16(af[mt][kb], bf[kb], acc, 0, 0, 0);
            #pragma unroll
            for (int r = 0; r < 4; ++r) {
                int row = base + mt*16 + l4*4 + r;
                if (row < N) qkv[(size_t)row*384 + col] = f2bf(acc[r] + bv);
            }
        }
    }
}

// ---------------- K2: sampled attention; ctx written into dead Q region ----
// Phase 1: lane=(k=lane&15, hp=lane>>4) -> softmax weights for heads hp, hp+4
//          into wave-local LDS (aw) + sample indices (ai). No barrier needed.
// Phase 2: lane=(g=lane>>4, c=lane&15); per batch b, lane loads 16B of V row
//          for sample kk=g+4b -> one inst = 4 rows x 256B = 1KB fully coalesced.
//          Reduce over g via 2 shfl_xor rounds; lanes<16 store 16B each.
__global__ __launch_bounds__(256) void k_attn(
        ushort* __restrict__ qkv, const int* __restrict__ samp, int N) {
    __shared__ float aw[4][8][17];              // [wave][head][k], padded
    __shared__ int   ai[4][16];                 // [wave][k] sample idx
    const int wave = threadIdx.x >> 6, lane = threadIdx.x & 63;
    const int n = blockIdx.x * 4 + wave;
    if (n >= N) return;
    const int k  = lane & 15;
    const int hp = lane >> 4;
    const int h0 = hp, h1 = hp + 4;

    const int idx = samp[(size_t)n*16 + k];
    const ushort* qrow = qkv + (size_t)n*384;
    const ushort* krow = qkv + (size_t)idx*384 + 128;

    float s0 = 0.f, s1 = 0.f;
    {
        const uint4* qa = (const uint4*)(qrow + h0*16);
        const uint4* ka = (const uint4*)(krow + h0*16);
        const uint4* qb = (const uint4*)(qrow + h1*16);
        const uint4* kb = (const uint4*)(krow + h1*16);
        #pragma unroll
        for (int i = 0; i < 2; ++i) {
            uint4 ua = qa[i], va = ka[i], ub = qb[i], vb = kb[i];
            s0 += bflo(ua.x)*bflo(va.x) + bfhi(ua.x)*bfhi(va.x)
                + bflo(ua.y)*bflo(va.y) + bfhi(ua.y)*bfhi(va.y)
                + bflo(ua.z)*bflo(va.z) + bfhi(ua.z)*bfhi(va.z)
                + bflo(ua.w)*bflo(va.w) + bfhi(ua.w)*bfhi(va.w);
            s1 += bflo(ub.x)*bflo(vb.x) + bfhi(ub.x)*bfhi(vb.x)
                + bflo(ub.y)*bflo(vb.y) + bfhi(ub.y)*bfhi(vb.y)
                + bflo(ub.z)*bflo(vb.z) + bfhi(ub.z)*bfhi(vb.z)
                + bflo(ub.w)*bflo(vb.w) + bfhi(ub.w)*bfhi(vb.w);
        }
    }
    s0 *= 0.25f; s1 *= 0.25f;     // 1/sqrt(16)
    float m0 = s0, m1 = s1;
    #pragma unroll
    for (int off = 1; off < 16; off <<= 1) {
        m0 = fmaxf(m0, __shfl_xor(m0, off));
        m1 = fmaxf(m1, __shfl_xor(m1, off));
    }
    float e0 = __expf(s0 - m0), e1 = __expf(s1 - m1);
    float d0 = e0, d1 = e1;
    #pragma unroll
    for (int off = 1; off < 16; off <<= 1) {
        d0 += __shfl_xor(d0, off);
        d1 += __shfl_xor(d1, off);
    }
    aw[wave][h0][k] = e0 / d0;
    aw[wave][h1][k] = e1 / d1;
    if (hp == 0) ai[wave][k] = idx;

    // ---- phase 2 ----
    const int c = lane & 15;        // 16B chunk of the 256B V row
    const int g = lane >> 4;        // k-group
    const int h = c >> 1;           // head owning dims c*8..c*8+7
    const ushort* vt = qkv + 256;   // V region base

    int rows[4];
    #pragma unroll
    for (int b = 0; b < 4; ++b) rows[b] = ai[wave][g + b*4];
    uint4 vv[4];
    #pragma unroll
    for (int b = 0; b < 4; ++b)
        vv[b] = *(const uint4*)(vt + (size_t)(unsigned)rows[b]*384 + c*8);
    float wk[4];
    #pragma unroll
    for (int b = 0; b < 4; ++b) wk[b] = aw[wave][h][g + b*4];

    float a8[8] = {0.f,0.f,0.f,0.f,0.f,0.f,0.f,0.f};
    #pragma unroll
    for (int b = 0; b < 4; ++b) {
        a8[0] = fmaf(wk[b], bflo(vv[b].x), a8[0]);
        a8[1] = fmaf(wk[b], bfhi(vv[b].x), a8[1]);
        a8[2] = fmaf(wk[b], bflo(vv[b].y), a8[2]);
        a8[3] = fmaf(wk[b], bfhi(vv[b].y), a8[3]);
        a8[4] = fmaf(wk[b], bflo(vv[b].z), a8[4]);
        a8[5] = fmaf(wk[b], bfhi(vv[b].z), a8[5]);
        a8[6] = fmaf(wk[b], bflo(vv[b].w), a8[6]);
        a8[7] = fmaf(wk[b], bfhi(vv[b].w), a8[7]);
    }
    #pragma unroll
    for (int i = 0; i < 8; ++i) {
        a8[i] += __shfl_xor(a8[i], 16);
        a8[i] += __shfl_xor(a8[i], 32);
    }
    if (lane < 16) {
        uint4 pack;
        pack.x = (unsigned)f2bf(a8[0]) | ((unsigned)f2bf(a8[1]) << 16);
        pack.y = (unsigned)f2bf(a8[2]) | ((unsigned)f2bf(a8[3]) << 16);
        pack.z = (unsigned)f2bf(a8[4]) | ((unsigned)f2bf(a8[5]) << 16);
        pack.w = (unsigned)f2bf(a8[6]) | ((unsigned)f2bf(a8[7]) << 16);
        *(uint4*)(qkv + (size_t)n*384 + c*8) = pack;   // ctx into dead Q region
    }
}

// ---------------- K3: fused tail ----------------
// out = LN2( y + relu(y@w1^T+b1)@w2^T + b2 ),  y = LN1(x + ctx@out_w^T + out_b)
// 64-row block, 4 waves. y lives only in swizzled LDS (16KB). FFN hidden dim
// processed in two 256-col passes through a 32KB swizzled LDS buffer.
__global__ __launch_bounds__(256) void k_tail(
        const ushort* __restrict__ ctx, const ushort* __restrict__ wob,
        const float* __restrict__ ob, const ushort* __restrict__ xb,
        const float* __restrict__ g1, const float* __restrict__ be1,
        const ushort* __restrict__ w1, const float* __restrict__ b1,
        const ushort* __restrict__ w2, const float* __restrict__ b2,
        const float* __restrict__ g2, const float* __restrict__ be2,
        float* __restrict__ out, int N) {
    __shared__ __align__(16) char smem[49152];
    char* yls  = smem;              // [64] rows * 256B (bf16 x128), XOR-swizzled
    char* h1ls = smem + 16384;      // [64] rows * 512B (bf16 x256), XOR-swizzled
    const int wave = threadIdx.x >> 6, lane = threadIdx.x & 63;
    const int l16 = lane & 15, l4 = lane >> 4;
    const int base = blockIdx.x * 64;
    const int mbase = base + wave * 16;

    // ---- out-proj + LN1 -> y in LDS ----
    {
        short8 af[4];
        int arow = mbase + l16;
        int arc = arow < N ? arow : N - 1;
        const ushort* p = ctx + (size_t)arc*384 + l4*8;
        #pragma unroll
        for (int kb = 0; kb < 4; ++kb) af[kb] = *(const short8*)(p + kb*32);
        f32x4 acc[8];
        #pragma unroll
        for (int nt = 0; nt < 8; ++nt) {
            int col = nt*16 + l16;
            const ushort* pw = wob + (size_t)col*128 + l4*8;
            f32x4 a = {0.f, 0.f, 0.f, 0.f};
            #pragma unroll
            for (int kb = 0; kb < 4; ++kb) {
                short8 bf = *(const short8*)(pw + kb*32);
                a = __builtin_amdgcn_mfma_f32_16x16x32_bf16(af[kb], bf, a, 0, 0, 0);
            }
            acc[nt] = a;
        }
        #pragma unroll
        for (int r = 0; r < 4; ++r) {
            int row = mbase + l4*4 + r;
            int rc = row < N ? row : N - 1;
            float s[8];
            float sum = 0.f, sq = 0.f;
            #pragma unroll
            for (int nt = 0; nt < 8; ++nt) {
                int col = nt*16 + l16;
                float v = acc[nt][r] + ob[col] + bf2f(xb[(size_t)rc*128 + col]);
                s[nt] = v; sum += v; sq += v*v;
            }
            #pragma unroll
            for (int off = 1; off < 16; off <<= 1) {
                sum += __shfl_xor(sum, off);
                sq  += __shfl_xor(sq, off);
            }
            float mean = sum * (1.f/128.f);
            float rstd = rsqrtf(sq*(1.f/128.f) - mean*mean + EPS);
            int lr = wave*16 + l4*4 + r;
            #pragma unroll
            for (int nt = 0; nt < 8; ++nt) {
                int col = nt*16 + l16;
                float yv = (s[nt]-mean)*rstd*g1[col] + be1[col];
                *(ushort*)(yls + lr*256 + ((col*2) ^ ((lr & 7) << 4))) = f2bf(yv);
            }
        }
    }
    __syncthreads();

    // ---- FFN: A-fragments of y from LDS (shared by both passes) ----
    short8 af2[4][4];
    #pragma unroll
    for (int mt = 0; mt < 4; ++mt) {
        int row = mt*16 + l16;
        #pragma unroll
        for (int kb = 0; kb < 4; ++kb) {
            int kbyte = kb*64 + l4*16;
            af2[mt][kb] = *(const short8*)(yls + row*256 + (kbyte ^ ((row & 7) << 4)));
        }
    }
    f32x4 acc2[4][2];
    #pragma unroll
    for (int mt = 0; mt < 4; ++mt)
        #pragma unroll
        for (int ntl = 0; ntl < 2; ++ntl) acc2[mt][ntl] = (f32x4){0.f,0.f,0.f,0.f};

    #pragma unroll
    for (int p2 = 0; p2 < 2; ++p2) {
        if (p2 == 1) __syncthreads();   // stage2-p0 reads done before overwrite
        // stage 1: hidden cols [p2*256, p2*256+256)
        #pragma unroll
        for (int i = 0; i < 4; ++i) {
            int lc = (wave*4 + i)*16 + l16;        // local col 0..255
            int gc = p2*256 + lc;
            const ushort* pw = w1 + (size_t)gc*128 + l4*8;
            short8 bf[4];
            #pragma unroll
            for (int kb = 0; kb < 4; ++kb) bf[kb] = *(const short8*)(pw + kb*32);
            float bv = b1[gc];
            #pragma unroll
            for (int mt = 0; mt < 4; ++mt) {
                f32x4 a = {0.f, 0.f, 0.f, 0.f};
                #pragma unroll
                for (int kb = 0; kb < 4; ++kb)
                    a = __builtin_amdgcn_mfma_f32_16x16x32_bf16(af2[mt][kb], bf[kb], a, 0, 0, 0);
                #pragma unroll
                for (int r = 0; r < 4; ++r) {
                    int lr = mt*16 + l4*4 + r;
                    float v = a[r] + bv;
                    v = v > 0.f ? v : 0.f;
                    *(ushort*)(h1ls + lr*512 + ((lc*2) ^ ((lr & 7) << 4))) = f2bf(v);
                }
            }
        }
        __syncthreads();
        // stage 2: wave n-tiles {2w,2w+1}, K=256 of this pass
        #pragma unroll 4
        for (int kb2 = 0; kb2 < 8; ++kb2) {
            short8 a2[4];
            #pragma unroll
            for (int mt = 0; mt < 4; ++mt) {
                int row = mt*16 + l16;
                int kbyte = kb2*64 + l4*16;
                a2[mt] = *(const short8*)(h1ls + row*512 + (kbyte ^ ((row & 7) << 4)));
            }
            #pragma unroll
            for (int ntl = 0; ntl < 2; ++ntl) {
                int col = (wave*2 + ntl)*16 + l16;
                short8 bfr = *(const short8*)(w2 + (size_t)col*512 + p2*256 + kb2*32 + l4*8);
                #pragma unroll
                for (int mt = 0; mt < 4; ++mt)
                    acc2[mt][ntl] = __builtin_amdgcn_mfma_f32_16x16x32_bf16(a2[mt], bfr, acc2[mt][ntl], 0, 0, 0);
            }
        }
    }

    // ---- s = y + ff + b2 (reads yls into regs) ----
    float sv[4][2][4];
    #pragma unroll
    for (int mt = 0; mt < 4; ++mt) {
        #pragma unroll
        for (int ntl = 0; ntl < 2; ++ntl) {
            int col = (wave*2 + ntl)*16 + l16;
            float bv = b2[col];
            #pragma unroll
            for (int r = 0; r < 4; ++r) {
                int lr = mt*16 + l4*4 + r;
                float yv = bf2f(*(const ushort*)(yls + lr*256 + ((col*2) ^ ((lr & 7) << 4))));
                sv[mt][ntl][r] = yv + acc2[mt][ntl][r] + bv;
            }
        }
    }
    __syncthreads();                 // all yls reads done before sbuf overwrite
    float* sbuf = (float*)smem;      // [64][132]
    #pragma unroll
    for (int mt = 0; mt < 4; ++mt)
        #pragma unroll
        for (int ntl = 0; ntl < 2; ++ntl) {
            int col = (wave*2 + ntl)*16 + l16;
            #pragma unroll
            for (int r = 0; r < 4; ++r) {
                int lr = mt*16 + l4*4 + r;
                sbuf[lr*132 + col] = sv[mt][ntl][r];
            }
        }
    __syncthreads();
    // ---- LN2: 4 threads per row ----
    {
        int row = threadIdx.x >> 2;     // 0..63
        int sub = threadIdx.x & 3;
        const float* sp = sbuf + row*132 + sub*32;
        float vals[32];
        float sum = 0.f, sq = 0.f;
        #pragma unroll
        for (int i = 0; i < 32; ++i) { float v = sp[i]; vals[i] = v; sum += v; sq += v*v; }
        sum += __shfl_xor(sum, 1); sq += __shfl_xor(sq, 1);
        sum += __shfl_xor(sum, 2); sq += __shfl_xor(sq, 2);
        float mean = sum * (1.f/128.f);
        float rstd = rsqrtf(sq*(1.f/128.f) - mean*mean + EPS);
        int grow = base + row;
        if (grow < N) {
            float* po = out + (size_t)grow*128 + sub*32;
            const float* pg = g2 + sub*32;
            const float* pb = be2 + sub*32;
            #pragma unroll
            for (int i = 0; i < 32; ++i)
                po[i] = (vals[i]-mean)*rstd*pg[i] + pb[i];
        }
    }
}

extern "C" void kernel_launch(void* const* d_in, const int* in_sizes, int n_in,
                              void* d_out, int out_size, void* d_ws, size_t ws_size,
                              hipStream_t stream) {
    (void)n_in; (void)out_size; (void)ws_size;
    const float* x   = (const float*)d_in[0];
    const int*   smp = (const int*)  d_in[1];
    const float* ipw = (const float*)d_in[2];
    const float* ipb = (const float*)d_in[3];
    const float* ow  = (const float*)d_in[4];
    const float* ob  = (const float*)d_in[5];
    const float* w1  = (const float*)d_in[6];
    const float* b1  = (const float*)d_in[7];
    const float* w2  = (const float*)d_in[8];
    const float* b2  = (const float*)d_in[9];
    const float* g1  = (const float*)d_in[10];
    const float* be1 = (const float*)d_in[11];
    const float* g2  = (const float*)d_in[12];
    const float* be2 = (const float*)d_in[13];
    const int N = in_sizes[0] / 128;

    ushort* qkv  = (ushort*)d_ws;                   // [N][384] bf16; Q region reused as ctx
    ushort* wqb  = qkv + (size_t)N * 384;           // 384*128
    ushort* wob  = wqb + 384*128;                   // 128*128
    ushort* w1b  = wob + 128*128;                   // 512*128
    ushort* w2b  = w1b + 512*128;                   // 128*512
    ushort* xb   = w2b + 128*512;                   // [N][128] bf16 x
    float*  outp = (float*)d_out;

    const int nb = (N + 63) / 64;
    k_prep <<<12500,     256, 0, stream>>>(ipw, ow, w1, w2, x, wqb, wob, w1b, w2b, xb, N*128);
    k_qkv  <<<nb,        256, 0, stream>>>(xb, wqb, ipb, qkv, N);
    k_attn <<<(N+3)/4,   256, 0, stream>>>(qkv, smp, N);
    k_tail <<<nb,        256, 0, stream>>>(qkv, wob, ob, xb, g1, be1,
                                           w1b, b1, w2b, b2, g2, be2, outp, N);
}